// Round 3
// baseline (1876.029 us; speedup 1.0000x reference)
//
#include <hip/hip_runtime.h>

#define N_DATA     131072
#define D_VECTOR   128
#define N_SUB      8
#define D_SUB      16
#define N_CLUSTERS 256
#define N_CODEBOOKS 64

// ws layout in 4-byte words
#define WS_LABELS 0
#define WS_PERM   (N_DATA)
#define WS_CNT    (2*N_DATA)
#define WS_CURSOR (2*N_DATA + 64)
#define WS_OFF    (2*N_DATA + 128)
#define WS_CNORM  (2*N_DATA + 256)                  // 131072 floats, numpy-order fp32
#define WS_CNSEL  (2*N_DATA + 256 + N_CODEBOOKS*N_SUB*N_CLUSTERS)  // 64 floats

// ---------------------------------------------------------------- precompute
// Emulates np.sum(cb*cb, axis=2) and np.sum(sel*sel, axis=0):
// strided-axis reduction = sequential over d, separate mul/add, fp32.
__global__ __launch_bounds__(256) void pq_precompute(
    const float* __restrict__ cb, const float* __restrict__ sel,
    float* __restrict__ cnorm_cb, float* __restrict__ cnorm_sel,
    int* __restrict__ cnt)
{
    int idx = blockIdx.x * 256 + threadIdx.x;       // 0..131071 = (l*8+s)*256+k
    int row = idx >> 8;
    int k   = idx & 255;
    const float* p = cb + (size_t)row * (D_SUB * N_CLUSTERS) + k;
    float sum = 0.f;
#pragma unroll
    for (int d = 0; d < D_SUB; d++) {
        float v = p[(size_t)d * N_CLUSTERS];
        sum = __fadd_rn(sum, __fmul_rn(v, v));      // no FMA: numpy mul-temp then add
    }
    cnorm_cb[idx] = sum;
    if (idx < N_CODEBOOKS) {
        float s2 = 0.f;
        for (int d = 0; d < D_VECTOR; d++) {
            float v = sel[d * N_CODEBOOKS + idx];
            s2 = __fadd_rn(s2, __fmul_rn(v, v));
        }
        cnorm_sel[idx] = s2;
        cnt[idx] = 0;
    }
}

// ---------------------------------------------------------------- stage 1: labels
// Emulates: d = xnorm[:,None] - 2.0*(x.T @ sel) + cnorm[None,:]; argmin axis=1.
// sgemm: sequential K (d=0..127) single-accumulator FMA chain.
// xnorm: sequential separate mul/add. Combine: ((xnorm - 2*cross) + cnorm).
__global__ __launch_bounds__(256) void pq_labels(
    const float* __restrict__ x, const float* __restrict__ sel,
    const float* __restrict__ cnorm_sel,
    int* __restrict__ labels, int* __restrict__ cnt)
{
    __shared__ int hist[N_CODEBOOKS];
    int tid = threadIdx.x;
    if (tid < N_CODEBOOKS) hist[tid] = 0;
    __syncthreads();

    int n = blockIdx.x * 256 + tid;
    float xm[D_VECTOR];
#pragma unroll
    for (int d = 0; d < D_VECTOR; d++) xm[d] = x[(size_t)d * N_DATA + n];

    // xnorm: sequential d, separate mul/add
    float xn = 0.f;
#pragma unroll
    for (int d = 0; d < D_VECTOR; d++) xn = __fadd_rn(xn, __fmul_rn(xm[d], xm[d]));

    float best = 1e30f;
    int   bl = 0;
    for (int l0 = 0; l0 < N_CODEBOOKS; l0 += 4) {
        float a0 = 0.f, a1 = 0.f, a2 = 0.f, a3 = 0.f;
#pragma unroll 8
        for (int d = 0; d < D_VECTOR; d++) {        // sequential-K FMA (BLAS microkernel)
            float xv = xm[d];
            const float* sp = sel + d * N_CODEBOOKS + l0;   // uniform scalar loads
            a0 = fmaf(xv, sp[0], a0);
            a1 = fmaf(xv, sp[1], a1);
            a2 = fmaf(xv, sp[2], a2);
            a3 = fmaf(xv, sp[3], a3);
        }
        float d0 = __fadd_rn(__fsub_rn(xn, __fmul_rn(2.0f, a0)), cnorm_sel[l0 + 0]);
        float d1 = __fadd_rn(__fsub_rn(xn, __fmul_rn(2.0f, a1)), cnorm_sel[l0 + 1]);
        float d2 = __fadd_rn(__fsub_rn(xn, __fmul_rn(2.0f, a2)), cnorm_sel[l0 + 2]);
        float d3 = __fadd_rn(__fsub_rn(xn, __fmul_rn(2.0f, a3)), cnorm_sel[l0 + 3]);
        // strict <, ascending index == np.argmin first-occurrence
        if (d0 < best) { best = d0; bl = l0 + 0; }
        if (d1 < best) { best = d1; bl = l0 + 1; }
        if (d2 < best) { best = d2; bl = l0 + 2; }
        if (d3 < best) { best = d3; bl = l0 + 3; }
    }
    labels[n] = bl;
    atomicAdd(&hist[bl], 1);
    __syncthreads();
    if (tid < N_CODEBOOKS) atomicAdd(&cnt[tid], hist[tid]);
}

// ---------------------------------------------------------------- scan (1 wave)
__global__ void pq_scan(const int* __restrict__ cnt, int* __restrict__ off, int* __restrict__ cursor)
{
    int tid = threadIdx.x;                           // 0..63
    int v = cnt[tid];
    int inc = v;
#pragma unroll
    for (int sft = 1; sft < 64; sft <<= 1) {
        int o = __shfl_up(inc, sft, 64);
        if (tid >= sft) inc += o;
    }
    int exc = inc - v;
    off[tid] = exc;
    cursor[tid] = exc;
    if (tid == 63) off[64] = inc;
}

// ---------------------------------------------------------------- counting-sort scatter
__global__ __launch_bounds__(256) void pq_scatter(
    const int* __restrict__ labels, int* __restrict__ cursor, int* __restrict__ perm)
{
    __shared__ int lcnt[N_CODEBOOKS];
    __shared__ int lbase[N_CODEBOOKS];
    int tid = threadIdx.x;
    if (tid < N_CODEBOOKS) lcnt[tid] = 0;
    __syncthreads();
    int base = blockIdx.x * 1024;
    int lv[4], slot[4];
#pragma unroll
    for (int i = 0; i < 4; i++) {
        int n = base + i * 256 + tid;
        int l = labels[n];
        lv[i] = l;
        slot[i] = atomicAdd(&lcnt[l], 1);
    }
    __syncthreads();
    if (tid < N_CODEBOOKS) lbase[tid] = atomicAdd(&cursor[tid], lcnt[tid]);
    __syncthreads();
#pragma unroll
    for (int i = 0; i < 4; i++) {
        int n = base + i * 256 + tid;
        perm[lbase[lv[i]] + slot[i]] = n;
    }
}

// ---------------------------------------------------------------- stage 2: PQ encode+decode
// Emulates np.einsum (optimize=False) sum-of-products: sequential d, separate
// mul/add, no FMA. dist = ((xnorm - 2*cross) + cnorm), all fp32 rounded.
__global__ __launch_bounds__(256) void pq_encode(
    const float* __restrict__ x, const float* __restrict__ cb,
    const float* __restrict__ cnorm_cb, const int* __restrict__ off,
    const int* __restrict__ perm, float* __restrict__ out)
{
    int tid = threadIdx.x;
    int start = blockIdx.x * 256;
    int end = start + 256;

    // first bucket intersecting [start,end)
    int lo = 0;
    for (int l = 1; l < N_CODEBOOKS; l++)
        if (off[l] <= start) lo = l;

    for (int l = lo; l < N_CODEBOOKS; l++) {
        int bkt_lo = off[l];
        if (bkt_lo >= end) break;
        int bkt_hi = off[l + 1];
        int a = bkt_lo < start ? start : bkt_lo;
        int b = bkt_hi < end ? bkt_hi : end;
        int pos = a + tid;
        if (pos < b) {
            int n = perm[pos];
            const float* cbl = cb + (size_t)l * (N_SUB * D_SUB * N_CLUSTERS);  // uniform
            const float* cnl = cnorm_cb + l * (N_SUB * N_CLUSTERS);            // uniform
            for (int s = 0; s < N_SUB; s++) {
                float xs[D_SUB];
#pragma unroll
                for (int d = 0; d < D_SUB; d++)
                    xs[d] = x[(size_t)(s * D_SUB + d) * N_DATA + n];

                // xnorm: sequential, separate mul/add
                float xn = 0.f;
#pragma unroll
                for (int d = 0; d < D_SUB; d++) xn = __fadd_rn(xn, __fmul_rn(xs[d], xs[d]));

                float best = 1e30f;
                int   bestk = 0;
                for (int kc = 0; kc < N_CLUSTERS; kc += 16) {
                    float acc[16];
#pragma unroll
                    for (int kk = 0; kk < 16; kk++) acc[kk] = 0.f;
#pragma unroll
                    for (int d = 0; d < D_SUB; d++) {
                        const float* rowp = cbl + (size_t)(s * D_SUB + d) * N_CLUSTERS + kc; // uniform
                        float xv = xs[d];
#pragma unroll
                        for (int kk = 0; kk < 16; kk++)
                            acc[kk] = __fadd_rn(acc[kk], __fmul_rn(xv, rowp[kk]));  // einsum sop
                    }
#pragma unroll
                    for (int kk = 0; kk < 16; kk++) {
                        float dist = __fadd_rn(__fsub_rn(xn, __fmul_rn(2.0f, acc[kk])),
                                               cnl[s * N_CLUSTERS + kc + kk]);
                        if (dist < best) { best = dist; bestk = kc + kk; }  // first occurrence
                    }
                }
#pragma unroll
                for (int d = 0; d < D_SUB; d++) {
                    out[(size_t)(s * D_SUB + d) * N_DATA + n] =
                        cbl[(size_t)(s * D_SUB + d) * N_CLUSTERS + bestk];
                }
            }
        }
    }
}

// ---------------------------------------------------------------- launcher
extern "C" void kernel_launch(void* const* d_in, const int* in_sizes, int n_in,
                              void* d_out, int out_size, void* d_ws, size_t ws_size,
                              hipStream_t stream)
{
    (void)in_sizes; (void)n_in; (void)out_size; (void)ws_size;
    const float* x   = (const float*)d_in[0];
    const float* cb  = (const float*)d_in[1];
    const float* sel = (const float*)d_in[2];
    float* out = (float*)d_out;

    int*   wsi    = (int*)d_ws;
    float* wsf    = (float*)d_ws;
    int*   labels = wsi + WS_LABELS;
    int*   perm   = wsi + WS_PERM;
    int*   cnt    = wsi + WS_CNT;
    int*   cursor = wsi + WS_CURSOR;
    int*   off    = wsi + WS_OFF;
    float* cnorm  = wsf + WS_CNORM;
    float* cnsel  = wsf + WS_CNSEL;

    hipLaunchKernelGGL(pq_precompute, dim3(512), dim3(256), 0, stream, cb, sel, cnorm, cnsel, cnt);
    hipLaunchKernelGGL(pq_labels, dim3(N_DATA / 256), dim3(256), 0, stream, x, sel, cnsel, labels, cnt);
    hipLaunchKernelGGL(pq_scan, dim3(1), dim3(64), 0, stream, cnt, off, cursor);
    hipLaunchKernelGGL(pq_scatter, dim3(N_DATA / 1024), dim3(256), 0, stream, labels, cursor, perm);
    hipLaunchKernelGGL(pq_encode, dim3(N_DATA / 256), dim3(256), 0, stream, x, cb, cnorm, off, perm, out);
}

// Round 4
// 783.230 us; speedup vs baseline: 2.3952x; 2.3952x over previous
//
#include <hip/hip_runtime.h>

#define N_DATA     131072
#define D_VECTOR   128
#define N_SUB      8
#define D_SUB      16
#define N_CLUSTERS 256
#define N_CODEBOOKS 64

// ws layout in 4-byte words (~2.6 MB total)
#define WS_LABELS 0
#define WS_PERM   (N_DATA)
#define WS_CNT    (2*N_DATA)
#define WS_CURSOR (2*N_DATA + 64)
#define WS_OFF    (2*N_DATA + 128)
#define WS_CNORM  (2*N_DATA + 256)                  // 131072 floats, numpy-order fp32
#define WS_CNSEL  (2*N_DATA + 256 + N_CODEBOOKS*N_SUB*N_CLUSTERS)
#define WS_CODES  (WS_CNSEL + 64)                   // 131072*8 bytes = 262144 words

// ---------------------------------------------------------------- precompute
// np.sum(cb*cb, axis=2) / np.sum(sel*sel, axis=0): sequential d, separate mul/add.
__global__ __launch_bounds__(256) void pq_precompute(
    const float* __restrict__ cb, const float* __restrict__ sel,
    float* __restrict__ cnorm_cb, float* __restrict__ cnorm_sel,
    int* __restrict__ cnt)
{
    int idx = blockIdx.x * 256 + threadIdx.x;       // 0..131071 = (l*8+s)*256+k
    int row = idx >> 8;
    int k   = idx & 255;
    const float* p = cb + (size_t)row * (D_SUB * N_CLUSTERS) + k;
    float sum = 0.f;
#pragma unroll
    for (int d = 0; d < D_SUB; d++) {
        float v = p[(size_t)d * N_CLUSTERS];
        sum = __fadd_rn(sum, __fmul_rn(v, v));
    }
    cnorm_cb[idx] = sum;
    if (idx < N_CODEBOOKS) {
        float s2 = 0.f;
        for (int d = 0; d < D_VECTOR; d++) {
            float v = sel[d * N_CODEBOOKS + idx];
            s2 = __fadd_rn(s2, __fmul_rn(v, v));
        }
        cnorm_sel[idx] = s2;
        cnt[idx] = 0;
    }
}

// ---------------------------------------------------------------- stage 1: labels + transpose
// Emulates d = xnorm - 2*(x.T@sel) + cnorm, argmin axis=1 (sgemm = sequential-K FMA).
// Side effect: writes xt[n][0..127] (transposed x) into d_out scratch, 512B/lane contiguous.
__global__ __launch_bounds__(256) void pq_labels(
    const float* __restrict__ x, const float* __restrict__ sel,
    const float* __restrict__ cnorm_sel,
    int* __restrict__ labels, int* __restrict__ cnt, float* __restrict__ xt)
{
    __shared__ int hist[N_CODEBOOKS];
    int tid = threadIdx.x;
    if (tid < N_CODEBOOKS) hist[tid] = 0;
    __syncthreads();

    int n = blockIdx.x * 256 + tid;
    float xm[D_VECTOR];
#pragma unroll
    for (int d = 0; d < D_VECTOR; d++) xm[d] = x[(size_t)d * N_DATA + n];  // coalesced

    // transpose write: 32 x float4, 512B contiguous per lane
    float4* dst = (float4*)(xt + (size_t)n * D_VECTOR);
#pragma unroll
    for (int i = 0; i < D_VECTOR / 4; i++)
        dst[i] = make_float4(xm[4*i], xm[4*i+1], xm[4*i+2], xm[4*i+3]);

    // xnorm: sequential d, separate mul/add
    float xn = 0.f;
#pragma unroll
    for (int d = 0; d < D_VECTOR; d++) xn = __fadd_rn(xn, __fmul_rn(xm[d], xm[d]));

    float best = 1e30f;
    int   bl = 0;
    for (int l0 = 0; l0 < N_CODEBOOKS; l0 += 4) {
        float a0 = 0.f, a1 = 0.f, a2 = 0.f, a3 = 0.f;
#pragma unroll 8
        for (int d = 0; d < D_VECTOR; d++) {        // sequential-K FMA (BLAS microkernel)
            float xv = xm[d];
            const float* sp = sel + d * N_CODEBOOKS + l0;   // uniform scalar loads
            a0 = fmaf(xv, sp[0], a0);
            a1 = fmaf(xv, sp[1], a1);
            a2 = fmaf(xv, sp[2], a2);
            a3 = fmaf(xv, sp[3], a3);
        }
        float d0 = __fadd_rn(__fsub_rn(xn, __fmul_rn(2.0f, a0)), cnorm_sel[l0 + 0]);
        float d1 = __fadd_rn(__fsub_rn(xn, __fmul_rn(2.0f, a1)), cnorm_sel[l0 + 1]);
        float d2 = __fadd_rn(__fsub_rn(xn, __fmul_rn(2.0f, a2)), cnorm_sel[l0 + 2]);
        float d3 = __fadd_rn(__fsub_rn(xn, __fmul_rn(2.0f, a3)), cnorm_sel[l0 + 3]);
        if (d0 < best) { best = d0; bl = l0 + 0; }
        if (d1 < best) { best = d1; bl = l0 + 1; }
        if (d2 < best) { best = d2; bl = l0 + 2; }
        if (d3 < best) { best = d3; bl = l0 + 3; }
    }
    labels[n] = bl;
    atomicAdd(&hist[bl], 1);
    __syncthreads();
    if (tid < N_CODEBOOKS) atomicAdd(&cnt[tid], hist[tid]);
}

// ---------------------------------------------------------------- scan (1 wave)
__global__ void pq_scan(const int* __restrict__ cnt, int* __restrict__ off, int* __restrict__ cursor)
{
    int tid = threadIdx.x;
    int v = cnt[tid];
    int inc = v;
#pragma unroll
    for (int sft = 1; sft < 64; sft <<= 1) {
        int o = __shfl_up(inc, sft, 64);
        if (tid >= sft) inc += o;
    }
    int exc = inc - v;
    off[tid] = exc;
    cursor[tid] = exc;
    if (tid == 63) off[64] = inc;
}

// ---------------------------------------------------------------- counting-sort scatter
__global__ __launch_bounds__(256) void pq_scatter(
    const int* __restrict__ labels, int* __restrict__ cursor, int* __restrict__ perm)
{
    __shared__ int lcnt[N_CODEBOOKS];
    __shared__ int lbase[N_CODEBOOKS];
    int tid = threadIdx.x;
    if (tid < N_CODEBOOKS) lcnt[tid] = 0;
    __syncthreads();
    int base = blockIdx.x * 1024;
    int lv[4], slot[4];
#pragma unroll
    for (int i = 0; i < 4; i++) {
        int n = base + i * 256 + tid;
        int l = labels[n];
        lv[i] = l;
        slot[i] = atomicAdd(&lcnt[l], 1);
    }
    __syncthreads();
    if (tid < N_CODEBOOKS) lbase[tid] = atomicAdd(&cursor[tid], lcnt[tid]);
    __syncthreads();
#pragma unroll
    for (int i = 0; i < 4; i++) {
        int n = base + i * 256 + tid;
        perm[lbase[lv[i]] + slot[i]] = n;
    }
}

// ---------------------------------------------------------------- stage 2: PQ encode (codes only)
// Grid: (N/256)*8 blocks; blockIdx -> (pos segment, subvector s).
// numpy-exact einsum: sequential d, separate mul/add, dist=((xn-2*acc)+cnorm), strict <.
__global__ __launch_bounds__(256) void pq_encode(
    const float* __restrict__ xt, const float* __restrict__ cb,
    const float* __restrict__ cnorm_cb, const int* __restrict__ off,
    const int* __restrict__ perm, unsigned char* __restrict__ codes)
{
    int tid = threadIdx.x;
    int s     = blockIdx.x & 7;
    int start = (blockIdx.x >> 3) * 256;
    int end   = start + 256;

    int lo = 0;
    for (int l = 1; l < N_CODEBOOKS; l++)
        if (off[l] <= start) lo = l;

    for (int l = lo; l < N_CODEBOOKS; l++) {
        int bkt_lo = off[l];
        if (bkt_lo >= end) break;
        int bkt_hi = off[l + 1];
        int a = bkt_lo < start ? start : bkt_lo;
        int b = bkt_hi < end ? bkt_hi : end;
        int pos = a + tid;
        if (pos < b) {
            int n = perm[pos];
            const float* cbl = cb + (size_t)l * (N_SUB * D_SUB * N_CLUSTERS);  // uniform
            const float* cnl = cnorm_cb + (l * N_SUB + s) * N_CLUSTERS;        // uniform

            // one fully-consumed 64B line per lane
            const float4* xp = (const float4*)(xt + (size_t)n * D_VECTOR + s * D_SUB);
            float4 v0 = xp[0], v1 = xp[1], v2 = xp[2], v3 = xp[3];
            float xs[D_SUB] = { v0.x, v0.y, v0.z, v0.w, v1.x, v1.y, v1.z, v1.w,
                                v2.x, v2.y, v2.z, v2.w, v3.x, v3.y, v3.z, v3.w };

            float xn = 0.f;
#pragma unroll
            for (int d = 0; d < D_SUB; d++) xn = __fadd_rn(xn, __fmul_rn(xs[d], xs[d]));

            float best = 1e30f;
            int   bestk = 0;
            for (int kc = 0; kc < N_CLUSTERS; kc += 16) {
                float acc[16];
#pragma unroll
                for (int kk = 0; kk < 16; kk++) acc[kk] = 0.f;
#pragma unroll
                for (int d = 0; d < D_SUB; d++) {
                    const float* rowp = cbl + (size_t)(s * D_SUB + d) * N_CLUSTERS + kc; // uniform
                    float xv = xs[d];
#pragma unroll
                    for (int kk = 0; kk < 16; kk++)
                        acc[kk] = __fadd_rn(acc[kk], __fmul_rn(xv, rowp[kk]));
                }
#pragma unroll
                for (int kk = 0; kk < 16; kk++) {
                    float dist = __fadd_rn(__fsub_rn(xn, __fmul_rn(2.0f, acc[kk])),
                                           cnl[kc + kk]);
                    if (dist < best) { best = dist; bestk = kc + kk; }
                }
            }
            codes[(size_t)n * N_SUB + s] = (unsigned char)bestk;
        }
    }
}

// ---------------------------------------------------------------- decode: coalesced out writes
__global__ __launch_bounds__(256) void pq_decode(
    const float* __restrict__ cb, const int* __restrict__ labels,
    const unsigned char* __restrict__ codes, float* __restrict__ out)
{
    int s = blockIdx.x & 7;
    int n = (blockIdx.x >> 3) * 256 + threadIdx.x;
    int l = labels[n];
    int k = codes[(size_t)n * N_SUB + s];
    const float* base = cb + ((size_t)(l * N_SUB + s) * D_SUB) * N_CLUSTERS + k;
#pragma unroll
    for (int dd = 0; dd < D_SUB; dd++)
        out[(size_t)(s * D_SUB + dd) * N_DATA + n] = base[(size_t)dd * N_CLUSTERS];
}

// ---------------------------------------------------------------- launcher
extern "C" void kernel_launch(void* const* d_in, const int* in_sizes, int n_in,
                              void* d_out, int out_size, void* d_ws, size_t ws_size,
                              hipStream_t stream)
{
    (void)in_sizes; (void)n_in; (void)out_size; (void)ws_size;
    const float* x   = (const float*)d_in[0];
    const float* cb  = (const float*)d_in[1];
    const float* sel = (const float*)d_in[2];
    float* out = (float*)d_out;

    int*   wsi    = (int*)d_ws;
    float* wsf    = (float*)d_ws;
    int*   labels = wsi + WS_LABELS;
    int*   perm   = wsi + WS_PERM;
    int*   cnt    = wsi + WS_CNT;
    int*   cursor = wsi + WS_CURSOR;
    int*   off    = wsi + WS_OFF;
    float* cnorm  = wsf + WS_CNORM;
    float* cnsel  = wsf + WS_CNSEL;
    unsigned char* codes = (unsigned char*)(wsi + WS_CODES);

    float* xt = out;   // d_out doubles as transpose scratch; pq_decode overwrites it fully

    hipLaunchKernelGGL(pq_precompute, dim3(512), dim3(256), 0, stream, cb, sel, cnorm, cnsel, cnt);
    hipLaunchKernelGGL(pq_labels, dim3(N_DATA / 256), dim3(256), 0, stream, x, sel, cnsel, labels, cnt, xt);
    hipLaunchKernelGGL(pq_scan, dim3(1), dim3(64), 0, stream, cnt, off, cursor);
    hipLaunchKernelGGL(pq_scatter, dim3(N_DATA / 1024), dim3(256), 0, stream, labels, cursor, perm);
    hipLaunchKernelGGL(pq_encode, dim3((N_DATA / 256) * N_SUB), dim3(256), 0, stream, xt, cb, cnorm, off, perm, codes);
    hipLaunchKernelGGL(pq_decode, dim3((N_DATA / 256) * N_SUB), dim3(256), 0, stream, cb, labels, codes, out);
}

// Round 5
// 780.244 us; speedup vs baseline: 2.4044x; 1.0038x over previous
//
#include <hip/hip_runtime.h>

#define N_DATA     131072
#define D_VECTOR   128
#define N_SUB      8
#define D_SUB      16
#define N_CLUSTERS 256
#define N_CODEBOOKS 64

// ws layout in 4-byte words (~3.6 MB total)
#define WS_LABELS 0
#define WS_PERM   (N_DATA)
#define WS_CNT    (2*N_DATA)
#define WS_CURSOR (2*N_DATA + 64)
#define WS_OFF    (2*N_DATA + 128)
#define WS_CNORM  (2*N_DATA + 256)                  // 131072 floats, numpy-order fp32
#define WS_CNSEL  (2*N_DATA + 256 + N_CODEBOOKS*N_SUB*N_CLUSTERS)
#define WS_CODES  (WS_CNSEL + 64)                   // 131072*8 bytes = 262144 words

// ---------------------------------------------------------------- precompute
// np.sum(cb*cb, axis=2) / np.sum(sel*sel, axis=0): sequential d, separate mul/add.
__global__ __launch_bounds__(256) void pq_precompute(
    const float* __restrict__ cb, const float* __restrict__ sel,
    float* __restrict__ cnorm_cb, float* __restrict__ cnorm_sel,
    int* __restrict__ cnt)
{
    int idx = blockIdx.x * 256 + threadIdx.x;       // 0..131071 = (l*8+s)*256+k
    int row = idx >> 8;
    int k   = idx & 255;
    const float* p = cb + (size_t)row * (D_SUB * N_CLUSTERS) + k;
    float sum = 0.f;
#pragma unroll
    for (int d = 0; d < D_SUB; d++) {
        float v = p[(size_t)d * N_CLUSTERS];
        sum = __fadd_rn(sum, __fmul_rn(v, v));
    }
    cnorm_cb[idx] = sum;
    if (idx < N_CODEBOOKS) {
        float s2 = 0.f;
        for (int d = 0; d < D_VECTOR; d++) {
            float v = sel[d * N_CODEBOOKS + idx];
            s2 = __fadd_rn(s2, __fmul_rn(v, v));
        }
        cnorm_sel[idx] = s2;
        cnt[idx] = 0;
    }
}

// ---------------------------------------------------------------- stage 1: labels + transpose
// Emulates d = xnorm - 2*(x.T@sel) + cnorm, argmin axis=1 (sgemm = sequential-K FMA).
// Side effect: writes xt[n][0..127] (transposed x) into d_out scratch.
__global__ __launch_bounds__(256) void pq_labels(
    const float* __restrict__ x, const float* __restrict__ sel,
    const float* __restrict__ cnorm_sel,
    int* __restrict__ labels, int* __restrict__ cnt, float* __restrict__ xt)
{
    __shared__ int hist[N_CODEBOOKS];
    int tid = threadIdx.x;
    if (tid < N_CODEBOOKS) hist[tid] = 0;
    __syncthreads();

    int n = blockIdx.x * 256 + tid;
    float xm[D_VECTOR];
#pragma unroll
    for (int d = 0; d < D_VECTOR; d++) xm[d] = x[(size_t)d * N_DATA + n];  // coalesced

    // transpose write: 32 x float4, 512B contiguous per lane
    float4* dst = (float4*)(xt + (size_t)n * D_VECTOR);
#pragma unroll
    for (int i = 0; i < D_VECTOR / 4; i++)
        dst[i] = make_float4(xm[4*i], xm[4*i+1], xm[4*i+2], xm[4*i+3]);

    // xnorm: sequential d, separate mul/add
    float xn = 0.f;
#pragma unroll
    for (int d = 0; d < D_VECTOR; d++) xn = __fadd_rn(xn, __fmul_rn(xm[d], xm[d]));

    float best = 1e30f;
    int   bl = 0;
    for (int l0 = 0; l0 < N_CODEBOOKS; l0 += 4) {
        float a0 = 0.f, a1 = 0.f, a2 = 0.f, a3 = 0.f;
#pragma unroll 8
        for (int d = 0; d < D_VECTOR; d++) {        // sequential-K FMA (BLAS microkernel)
            float xv = xm[d];
            const float* sp = sel + d * N_CODEBOOKS + l0;   // uniform scalar loads
            a0 = fmaf(xv, sp[0], a0);
            a1 = fmaf(xv, sp[1], a1);
            a2 = fmaf(xv, sp[2], a2);
            a3 = fmaf(xv, sp[3], a3);
        }
        float d0 = __fadd_rn(__fsub_rn(xn, __fmul_rn(2.0f, a0)), cnorm_sel[l0 + 0]);
        float d1 = __fadd_rn(__fsub_rn(xn, __fmul_rn(2.0f, a1)), cnorm_sel[l0 + 1]);
        float d2 = __fadd_rn(__fsub_rn(xn, __fmul_rn(2.0f, a2)), cnorm_sel[l0 + 2]);
        float d3 = __fadd_rn(__fsub_rn(xn, __fmul_rn(2.0f, a3)), cnorm_sel[l0 + 3]);
        if (d0 < best) { best = d0; bl = l0 + 0; }
        if (d1 < best) { best = d1; bl = l0 + 1; }
        if (d2 < best) { best = d2; bl = l0 + 2; }
        if (d3 < best) { best = d3; bl = l0 + 3; }
    }
    labels[n] = bl;
    atomicAdd(&hist[bl], 1);
    __syncthreads();
    if (tid < N_CODEBOOKS) atomicAdd(&cnt[tid], hist[tid]);
}

// ---------------------------------------------------------------- scan (1 wave)
__global__ void pq_scan(const int* __restrict__ cnt, int* __restrict__ off, int* __restrict__ cursor)
{
    int tid = threadIdx.x;
    int v = cnt[tid];
    int inc = v;
#pragma unroll
    for (int sft = 1; sft < 64; sft <<= 1) {
        int o = __shfl_up(inc, sft, 64);
        if (tid >= sft) inc += o;
    }
    int exc = inc - v;
    off[tid] = exc;
    cursor[tid] = exc;
    if (tid == 63) off[64] = inc;
}

// ---------------------------------------------------------------- counting-sort scatter
__global__ __launch_bounds__(256) void pq_scatter(
    const int* __restrict__ labels, int* __restrict__ cursor, int* __restrict__ perm)
{
    __shared__ int lcnt[N_CODEBOOKS];
    __shared__ int lbase[N_CODEBOOKS];
    int tid = threadIdx.x;
    if (tid < N_CODEBOOKS) lcnt[tid] = 0;
    __syncthreads();
    int base = blockIdx.x * 1024;
    int lv[4], slot[4];
#pragma unroll
    for (int i = 0; i < 4; i++) {
        int n = base + i * 256 + tid;
        int l = labels[n];
        lv[i] = l;
        slot[i] = atomicAdd(&lcnt[l], 1);
    }
    __syncthreads();
    if (tid < N_CODEBOOKS) lbase[tid] = atomicAdd(&cursor[tid], lcnt[tid]);
    __syncthreads();
#pragma unroll
    for (int i = 0; i < 4; i++) {
        int n = base + i * 256 + tid;
        perm[lbase[lv[i]] + slot[i]] = n;
    }
}

// ---------------------------------------------------------------- stage 2: PQ encode (codes only)
// v3: uniform control flow (clamped pos, predicated store) so codebook reads are
// provably wave-uniform -> s_load on the scalar pipe, off the VALU issue path.
// Arithmetic is numpy-exact: sequential d, separate mul/add, strict-< argmin.
__global__ __launch_bounds__(256) void pq_encode(
    const float* __restrict__ xt, const float* __restrict__ cb,
    const float* __restrict__ cnorm_cb, const int* __restrict__ off,
    const int* __restrict__ perm, unsigned char* __restrict__ codes)
{
    int tid = threadIdx.x;
    int s     = blockIdx.x & 7;
    int start = (blockIdx.x >> 3) * 256;
    int end   = start + 256;

    int lo = 0;
    for (int l = 1; l < N_CODEBOOKS; l++)
        if (off[l] <= start) lo = l;

    for (int l = lo; l < N_CODEBOOKS; l++) {
        int bkt_lo = off[l];
        if (bkt_lo >= end) break;
        int bkt_hi = off[l + 1];
        int a = bkt_lo < start ? start : bkt_lo;
        int b = bkt_hi < end ? bkt_hi : end;
        if (b > a) {                                  // uniform branch
            int pos  = a + tid;
            bool act = pos < b;
            int pc   = act ? pos : (b - 1);           // clamp: all lanes compute
            int n    = perm[pc];

            int lu = __builtin_amdgcn_readfirstlane(l);            // force SGPR
            const float* cbs = cb + ((size_t)(lu * N_SUB + s)) * (D_SUB * N_CLUSTERS);
            const float* cns = cnorm_cb + (lu * N_SUB + s) * N_CLUSTERS;

            // one fully-consumed 64B line per lane
            const float4* xp = (const float4*)(xt + (size_t)n * D_VECTOR + s * D_SUB);
            float4 v0 = xp[0], v1 = xp[1], v2 = xp[2], v3 = xp[3];
            float xs[D_SUB] = { v0.x, v0.y, v0.z, v0.w, v1.x, v1.y, v1.z, v1.w,
                                v2.x, v2.y, v2.z, v2.w, v3.x, v3.y, v3.z, v3.w };

            float xn = 0.f;
#pragma unroll
            for (int d = 0; d < D_SUB; d++) xn = __fadd_rn(xn, __fmul_rn(xs[d], xs[d]));

            float best = 1e30f;
            int   bestk = 0;
            for (int kc = 0; kc < N_CLUSTERS; kc += 16) {
                // float2-shaped accumulators: componentwise exact mul/add (packable)
                float2 acc[8];
#pragma unroll
                for (int j = 0; j < 8; j++) acc[j] = make_float2(0.f, 0.f);
#pragma unroll
                for (int d = 0; d < D_SUB; d++) {
                    const float2* row2 = (const float2*)(cbs + (size_t)d * N_CLUSTERS + kc); // uniform
                    float xv = xs[d];
#pragma unroll
                    for (int j = 0; j < 8; j++) {
                        float2 r = row2[j];
                        acc[j].x = __fadd_rn(acc[j].x, __fmul_rn(xv, r.x));
                        acc[j].y = __fadd_rn(acc[j].y, __fmul_rn(xv, r.y));
                    }
                }
#pragma unroll
                for (int j = 0; j < 8; j++) {
                    float dx = __fadd_rn(__fsub_rn(xn, __fmul_rn(2.0f, acc[j].x)), cns[kc + 2*j]);
                    float dy = __fadd_rn(__fsub_rn(xn, __fmul_rn(2.0f, acc[j].y)), cns[kc + 2*j + 1]);
                    if (dx < best) { best = dx; bestk = kc + 2*j; }
                    if (dy < best) { best = dy; bestk = kc + 2*j + 1; }
                }
            }
            if (act) codes[(size_t)n * N_SUB + s] = (unsigned char)bestk;
        }
    }
}

// ---------------------------------------------------------------- decode: coalesced out writes
__global__ __launch_bounds__(256) void pq_decode(
    const float* __restrict__ cb, const int* __restrict__ labels,
    const unsigned char* __restrict__ codes, float* __restrict__ out)
{
    int s = blockIdx.x & 7;
    int n = (blockIdx.x >> 3) * 256 + threadIdx.x;
    int l = labels[n];
    int k = codes[(size_t)n * N_SUB + s];
    const float* base = cb + ((size_t)(l * N_SUB + s) * D_SUB) * N_CLUSTERS + k;
#pragma unroll
    for (int dd = 0; dd < D_SUB; dd++)
        out[(size_t)(s * D_SUB + dd) * N_DATA + n] = base[(size_t)dd * N_CLUSTERS];
}

// ---------------------------------------------------------------- launcher
extern "C" void kernel_launch(void* const* d_in, const int* in_sizes, int n_in,
                              void* d_out, int out_size, void* d_ws, size_t ws_size,
                              hipStream_t stream)
{
    (void)in_sizes; (void)n_in; (void)out_size; (void)ws_size;
    const float* x   = (const float*)d_in[0];
    const float* cb  = (const float*)d_in[1];
    const float* sel = (const float*)d_in[2];
    float* out = (float*)d_out;

    int*   wsi    = (int*)d_ws;
    float* wsf    = (float*)d_ws;
    int*   labels = wsi + WS_LABELS;
    int*   perm   = wsi + WS_PERM;
    int*   cnt    = wsi + WS_CNT;
    int*   cursor = wsi + WS_CURSOR;
    int*   off    = wsi + WS_OFF;
    float* cnorm  = wsf + WS_CNORM;
    float* cnsel  = wsf + WS_CNSEL;
    unsigned char* codes = (unsigned char*)(wsi + WS_CODES);

    float* xt = out;   // d_out doubles as transpose scratch; pq_decode overwrites it fully

    hipLaunchKernelGGL(pq_precompute, dim3(512), dim3(256), 0, stream, cb, sel, cnorm, cnsel, cnt);
    hipLaunchKernelGGL(pq_labels, dim3(N_DATA / 256), dim3(256), 0, stream, x, sel, cnsel, labels, cnt, xt);
    hipLaunchKernelGGL(pq_scan, dim3(1), dim3(64), 0, stream, cnt, off, cursor);
    hipLaunchKernelGGL(pq_scatter, dim3(N_DATA / 1024), dim3(256), 0, stream, labels, cursor, perm);
    hipLaunchKernelGGL(pq_encode, dim3((N_DATA / 256) * N_SUB), dim3(256), 0, stream, xt, cb, cnorm, off, perm, codes);
    hipLaunchKernelGGL(pq_decode, dim3((N_DATA / 256) * N_SUB), dim3(256), 0, stream, cb, labels, codes, out);
}

// Round 6
// 702.142 us; speedup vs baseline: 2.6719x; 1.1112x over previous
//
#include <hip/hip_runtime.h>

#define N_DATA     131072
#define D_VECTOR   128
#define N_SUB      8
#define D_SUB      16
#define N_CLUSTERS 256
#define N_CODEBOOKS 64

typedef float v2f __attribute__((ext_vector_type(2)));

// ws layout in 4-byte words (~3.2 MB total)
#define WS_LABELS 0
#define WS_PERM   (N_DATA)
#define WS_CNT    (2*N_DATA)
#define WS_CURSOR (2*N_DATA + 64)
#define WS_OFF    (2*N_DATA + 128)
#define WS_CNORM  (2*N_DATA + 256)                  // 131072 floats, numpy-order fp32
#define WS_CNSEL  (2*N_DATA + 256 + N_CODEBOOKS*N_SUB*N_CLUSTERS)
#define WS_CODES  (WS_CNSEL + 64)                   // 131072*8 bytes = 262144 words
#define WS_XNORM  (WS_CODES + 262144)               // 131072 floats

// ---------------------------------------------------------------- precompute
// np.sum(cb*cb, axis=2) / np.sum(sel*sel, axis=0): sequential d, separate mul/add.
__global__ __launch_bounds__(256) void pq_precompute(
    const float* __restrict__ cb, const float* __restrict__ sel,
    float* __restrict__ cnorm_cb, float* __restrict__ cnorm_sel,
    int* __restrict__ cnt)
{
    int idx = blockIdx.x * 256 + threadIdx.x;       // 0..131071 = (l*8+s)*256+k
    int row = idx >> 8;
    int k   = idx & 255;
    const float* p = cb + (size_t)row * (D_SUB * N_CLUSTERS) + k;
    float sum = 0.f;
#pragma unroll
    for (int d = 0; d < D_SUB; d++) {
        float v = p[(size_t)d * N_CLUSTERS];
        sum = __fadd_rn(sum, __fmul_rn(v, v));
    }
    cnorm_cb[idx] = sum;
    if (idx < N_CODEBOOKS) {
        float s2 = 0.f;
        for (int d = 0; d < D_VECTOR; d++) {
            float v = sel[d * N_CODEBOOKS + idx];
            s2 = __fadd_rn(s2, __fmul_rn(v, v));
        }
        cnorm_sel[idx] = s2;
        cnt[idx] = 0;
    }
}

// ---------------------------------------------------------------- transpose + xnorm
// Reads x [d][n] coalesced, writes xt[n][d] (row per thread) + xnorm[n]
// (numpy strided reduction: sequential d, separate mul/add).
__global__ __launch_bounds__(256, 2) void pq_transpose(
    const float* __restrict__ x, float* __restrict__ xt, float* __restrict__ xnorms)
{
    int n = blockIdx.x * 256 + threadIdx.x;
    float xm[D_VECTOR];
#pragma unroll
    for (int d = 0; d < D_VECTOR; d++) xm[d] = x[(size_t)d * N_DATA + n];  // coalesced

    float4* dst = (float4*)(xt + (size_t)n * D_VECTOR);
#pragma unroll
    for (int i = 0; i < D_VECTOR / 4; i++)
        dst[i] = make_float4(xm[4*i], xm[4*i+1], xm[4*i+2], xm[4*i+3]);

    float xn = 0.f;
#pragma unroll
    for (int d = 0; d < D_VECTOR; d++) xn = __fadd_rn(xn, __fmul_rn(xm[d], xm[d]));
    xnorms[n] = xn;
}

// ---------------------------------------------------------------- stage 1: labels
// d = xnorm - 2*(x.T@sel) + cnorm, argmin axis=1. sgemm = per-l sequential-K fmaf
// chain; pk_fma packs l-pairs (componentwise fma == fmaf, bit-exact).
__global__ __launch_bounds__(256, 4) void pq_labels2(
    const float* __restrict__ x, const float* __restrict__ sel,
    const float* __restrict__ cnorm_sel, const float* __restrict__ xnorms,
    int* __restrict__ labels, int* __restrict__ cnt)
{
    __shared__ int hist[N_CODEBOOKS];
    int tid = threadIdx.x;
    if (tid < N_CODEBOOKS) hist[tid] = 0;
    __syncthreads();

    int n = blockIdx.x * 256 + tid;

    v2f acc[32];
#pragma unroll
    for (int lp = 0; lp < 32; lp++) acc[lp] = (v2f){0.f, 0.f};

    for (int d = 0; d < D_VECTOR; d++) {
        float xv = x[(size_t)d * N_DATA + n];        // coalesced
        v2f xv2 = (v2f){xv, xv};
        const v2f* sp = (const v2f*)(sel + d * N_CODEBOOKS);  // uniform
#pragma unroll
        for (int lp = 0; lp < 32; lp++)
            acc[lp] = __builtin_elementwise_fma(xv2, sp[lp], acc[lp]);  // v_pk_fma_f32
    }

    float xn = xnorms[n];
    float best = 1e30f;
    int   bl = 0;
#pragma unroll
    for (int lp = 0; lp < 32; lp++) {
        float dx = __fadd_rn(__fsub_rn(xn, __fmul_rn(2.0f, acc[lp].x)), cnorm_sel[2*lp]);
        float dy = __fadd_rn(__fsub_rn(xn, __fmul_rn(2.0f, acc[lp].y)), cnorm_sel[2*lp + 1]);
        if (dx < best) { best = dx; bl = 2*lp; }
        if (dy < best) { best = dy; bl = 2*lp + 1; }
    }
    labels[n] = bl;
    atomicAdd(&hist[bl], 1);
    __syncthreads();
    if (tid < N_CODEBOOKS) atomicAdd(&cnt[tid], hist[tid]);
}

// ---------------------------------------------------------------- scan (1 wave)
__global__ void pq_scan(const int* __restrict__ cnt, int* __restrict__ off, int* __restrict__ cursor)
{
    int tid = threadIdx.x;
    int v = cnt[tid];
    int inc = v;
#pragma unroll
    for (int sft = 1; sft < 64; sft <<= 1) {
        int o = __shfl_up(inc, sft, 64);
        if (tid >= sft) inc += o;
    }
    int exc = inc - v;
    off[tid] = exc;
    cursor[tid] = exc;
    if (tid == 63) off[64] = inc;
}

// ---------------------------------------------------------------- counting-sort scatter
__global__ __launch_bounds__(256) void pq_scatter(
    const int* __restrict__ labels, int* __restrict__ cursor, int* __restrict__ perm)
{
    __shared__ int lcnt[N_CODEBOOKS];
    __shared__ int lbase[N_CODEBOOKS];
    int tid = threadIdx.x;
    if (tid < N_CODEBOOKS) lcnt[tid] = 0;
    __syncthreads();
    int base = blockIdx.x * 1024;
    int lv[4], slot[4];
#pragma unroll
    for (int i = 0; i < 4; i++) {
        int n = base + i * 256 + tid;
        int l = labels[n];
        lv[i] = l;
        slot[i] = atomicAdd(&lcnt[l], 1);
    }
    __syncthreads();
    if (tid < N_CODEBOOKS) lbase[tid] = atomicAdd(&cursor[tid], lcnt[tid]);
    __syncthreads();
#pragma unroll
    for (int i = 0; i < 4; i++) {
        int n = base + i * 256 + tid;
        perm[lbase[lv[i]] + slot[i]] = n;
    }
}

// monotone fp32 -> uint key; maps -0.0 and +0.0 to the same key.
__device__ __forceinline__ unsigned int fkey(float f)
{
    unsigned int b = __float_as_uint(f);
    unsigned int m = (unsigned int)((int)b >> 31) | 0x80000000u;
    unsigned int u = b ^ m;
    if (b == 0x80000000u) u = 0x80000000u;   // -0.0 == +0.0
    return u;
}

// ---------------------------------------------------------------- stage 2: PQ encode v4
// Wave = one point at a time; lane L holds codebook k in [4L,4L+4) x 16 d in
// VGPRs (reloaded only on label change). Inner loop: packed fp32 mul/add
// (componentwise == __fmul_rn/__fadd_rn, numpy-exact), zero loads.
// Argmin: ordered-uint key, shfl_xor min butterfly, lowest-lane/lowest-j ties
// == numpy first-occurrence.
__global__ __launch_bounds__(256, 4) void pq_encode(
    const float* __restrict__ xt, const float* __restrict__ cb,
    const float* __restrict__ cnorm_cb, const int* __restrict__ labels,
    const int* __restrict__ perm, unsigned char* __restrict__ codes)
{
    int tid  = threadIdx.x;
    int lane = tid & 63;
    int w    = tid >> 6;
    int s    = blockIdx.x & 7;
    int seg  = blockIdx.x >> 3;
    int base = seg * 256 + w * 64;

    int lcur = -1;
    v2f cbA[D_SUB], cbB[D_SUB];
    v2f cnA = (v2f){0.f, 0.f}, cnB = (v2f){0.f, 0.f};

    for (int i = 0; i < 64; i++) {
        int pos = base + i;
        int n = perm[pos];                 // wave-uniform broadcast load
        int l = labels[n];                 // wave-uniform

        if (l != lcur) {                   // uniform branch; ~1-2x per 64 points
            lcur = l;
            const float* cbs = cb + (size_t)(l * N_SUB + s) * (D_SUB * N_CLUSTERS);
#pragma unroll
            for (int d = 0; d < D_SUB; d++) {
                float4 v = *(const float4*)(cbs + (size_t)d * N_CLUSTERS + lane * 4);
                cbA[d] = (v2f){v.x, v.y};
                cbB[d] = (v2f){v.z, v.w};
            }
            float4 c = *(const float4*)(cnorm_cb + (size_t)(l * N_SUB + s) * N_CLUSTERS + lane * 4);
            cnA = (v2f){c.x, c.y};
            cnB = (v2f){c.z, c.w};
        }

        const float4* xp = (const float4*)(xt + (size_t)n * D_VECTOR + s * D_SUB);
        float4 x0 = xp[0], x1 = xp[1], x2 = xp[2], x3 = xp[3];
        float xs[D_SUB] = { x0.x, x0.y, x0.z, x0.w, x1.x, x1.y, x1.z, x1.w,
                            x2.x, x2.y, x2.z, x2.w, x3.x, x3.y, x3.z, x3.w };

        // xnorm: numpy strided reduction (sequential d, separate mul/add)
        float xn = 0.f;
#pragma unroll
        for (int d = 0; d < D_SUB; d++) xn = __fadd_rn(xn, __fmul_rn(xs[d], xs[d]));

        v2f a0 = (v2f){0.f, 0.f}, a1 = (v2f){0.f, 0.f};
        {
#pragma clang fp contract(off)
#pragma unroll
            for (int d = 0; d < D_SUB; d++) {
                v2f xv = (v2f){xs[d], xs[d]};
                a0 = a0 + xv * cbA[d];     // v_pk_mul_f32 + v_pk_add_f32, exact
                a1 = a1 + xv * cbB[d];
            }
            v2f xnv = (v2f){xn, xn};
            v2f twov = (v2f){2.f, 2.f};
            v2f d0 = (xnv - twov * a0) + cnA;   // ((xn - 2*acc) + cn), rounded per op
            v2f d1 = (xnv - twov * a1) + cnB;

            unsigned int k0 = fkey(d0.x), k1 = fkey(d0.y);
            unsigned int k2 = fkey(d1.x), k3 = fkey(d1.y);
            unsigned int m = min(min(k0, k1), min(k2, k3));
            int j = (m == k0) ? 0 : (m == k1) ? 1 : (m == k2) ? 2 : 3;  // first j on ties

            unsigned int g = m;
#pragma unroll
            for (int mask = 1; mask < 64; mask <<= 1)
                g = min(g, (unsigned int)__shfl_xor((int)g, mask));

            unsigned long long bal = __ballot(m == g);
            int winner = __ffsll((long long)bal) - 1;   // lowest lane = lowest k
            int myk = (lane << 2) | j;
            int kwin = __shfl(myk, winner);
            if (lane == 0) codes[(size_t)n * N_SUB + s] = (unsigned char)kwin;
        }
    }
}

// ---------------------------------------------------------------- decode: coalesced out writes
__global__ __launch_bounds__(256) void pq_decode(
    const float* __restrict__ cb, const int* __restrict__ labels,
    const unsigned char* __restrict__ codes, float* __restrict__ out)
{
    int s = blockIdx.x & 7;
    int n = (blockIdx.x >> 3) * 256 + threadIdx.x;
    int l = labels[n];
    int k = codes[(size_t)n * N_SUB + s];
    const float* base = cb + ((size_t)(l * N_SUB + s) * D_SUB) * N_CLUSTERS + k;
#pragma unroll
    for (int dd = 0; dd < D_SUB; dd++)
        out[(size_t)(s * D_SUB + dd) * N_DATA + n] = base[(size_t)dd * N_CLUSTERS];
}

// ---------------------------------------------------------------- launcher
extern "C" void kernel_launch(void* const* d_in, const int* in_sizes, int n_in,
                              void* d_out, int out_size, void* d_ws, size_t ws_size,
                              hipStream_t stream)
{
    (void)in_sizes; (void)n_in; (void)out_size; (void)ws_size;
    const float* x   = (const float*)d_in[0];
    const float* cb  = (const float*)d_in[1];
    const float* sel = (const float*)d_in[2];
    float* out = (float*)d_out;

    int*   wsi    = (int*)d_ws;
    float* wsf    = (float*)d_ws;
    int*   labels = wsi + WS_LABELS;
    int*   perm   = wsi + WS_PERM;
    int*   cnt    = wsi + WS_CNT;
    int*   cursor = wsi + WS_CURSOR;
    int*   off    = wsi + WS_OFF;
    float* cnorm  = wsf + WS_CNORM;
    float* cnsel  = wsf + WS_CNSEL;
    unsigned char* codes = (unsigned char*)(wsi + WS_CODES);
    float* xnorms = wsf + WS_XNORM;

    float* xt = out;   // d_out doubles as transpose scratch; pq_decode overwrites it fully

    hipLaunchKernelGGL(pq_precompute, dim3(512), dim3(256), 0, stream, cb, sel, cnorm, cnsel, cnt);
    hipLaunchKernelGGL(pq_transpose, dim3(N_DATA / 256), dim3(256), 0, stream, x, xt, xnorms);
    hipLaunchKernelGGL(pq_labels2, dim3(N_DATA / 256), dim3(256), 0, stream, x, sel, cnsel, xnorms, labels, cnt);
    hipLaunchKernelGGL(pq_scan, dim3(1), dim3(64), 0, stream, cnt, off, cursor);
    hipLaunchKernelGGL(pq_scatter, dim3(N_DATA / 1024), dim3(256), 0, stream, labels, cursor, perm);
    hipLaunchKernelGGL(pq_encode, dim3((N_DATA / 256) * N_SUB), dim3(256), 0, stream, xt, cb, cnorm, labels, perm, codes);
    hipLaunchKernelGGL(pq_decode, dim3((N_DATA / 256) * N_SUB), dim3(256), 0, stream, cb, labels, codes, out);
}